// Round 3
// baseline (265.645 us; speedup 1.0000x reference)
//
#include <hip/hip_runtime.h>

// LRN (buggy-keras window) on x:(64,56,56,192) fp32 NHWC.
// window for channel c: [max(c-2,0), min(2c+3, C)); scale=(sum*2e-5+1)^0.75; out=x/scale
//
// R6: persistent grid-stride + register double-buffer prefetch.
// R3 (LDS), R4 (bpermute), R5 (coalesced) all ~91us / 2.55 TB/s, all pipes idle ->
// wall is per-wave load DUTY CYCLE: one-shot waves have loads in flight only during
// their first ~900 cycles, then compute/store/die (plus 12544-block churn). Fix:
// 1792 blocks (7/CU), each wave-slot processes exactly 7 pixel-groups (50176/7168=7.0),
// issuing next iteration's 3 coalesced loads BEFORE computing the current one ->
// every wave keeps ~3KB outstanding continuously; ~84KB/CU sustained in flight.
// Stores are nontemporal (output never re-read; don't churn LLC against input lines).
// Compute body = R5 (interleaved ownership, 3x16-wide scan, 12 bpermute gather).
// (1+e)^-0.75 via cubic series (e<=~0.01 -> err <1e-7 vs thr 0.108).

constexpr int   C     = 192;
constexpr int   LPP   = 16;             // lanes per pixel
constexpr int   PPW   = 4;              // pixels per wave per iteration
constexpr int   WPB   = 4;              // waves per block
constexpr int   BLOCK = 256;
constexpr int   GRID  = 1792;           // 7168 wave-slots -> exactly 7 iters each
constexpr float AON   = 0.0001f / 5.0f; // alpha/n = 2e-5

typedef float f32x4 __attribute__((ext_vector_type(4)));

__device__ __forceinline__ float bperm(int byteaddr, float v) {
  return __int_as_float(__builtin_amdgcn_ds_bpermute(byteaddr, __float_as_int(v)));
}

__device__ __forceinline__ void nt_store4(float a, float b, float c, float d,
                                          float4* __restrict__ p) {
  f32x4 t = {a, b, c, d};
  __builtin_nontemporal_store(t, (f32x4*)p);
}

// Compute + store one pixel-iteration from registers. u0/u1/u2 = float4s {sub,16+sub,32+sub}
// of this lane's pixel row; ob = pixel row base (float4*); a0/a1/a2 = bpermute byte addrs.
__device__ __forceinline__ void lrn_body(const float4 u0, const float4 u1, const float4 u2,
                                         float4* __restrict__ ob, int sub,
                                         int a0, int a1, int a2) {
  float xs[3][4] = {{u0.x, u0.y, u0.z, u0.w},
                    {u1.x, u1.y, u1.z, u1.w},
                    {u2.x, u2.y, u2.z, u2.w}};

  // ---- chunk sums q[s] over slot s (chunk index m = 16s + sub) ----
  float q[3];
#pragma unroll
  for (int s = 0; s < 3; ++s)
    q[s] = fmaf(xs[s][0], xs[s][0],
           fmaf(xs[s][1], xs[s][1],
           fmaf(xs[s][2], xs[s][2], xs[s][3] * xs[s][3])));

  // ---- three independent 16-wide inclusive scans ----
  float i0 = q[0], i1 = q[1], i2 = q[2];
#pragma unroll
  for (int off = 1; off < LPP; off <<= 1) {
    const float t0 = __shfl_up(i0, off, LPP);
    const float t1 = __shfl_up(i1, off, LPP);
    const float t2 = __shfl_up(i2, off, LPP);
    if (sub >= off) { i0 += t0; i1 += t1; i2 += t2; }
  }
  const float T0 = __shfl(i0, LPP - 1, LPP);
  const float T1 = __shfl(i1, LPP - 1, LPP);
  const float T2 = __shfl(i2, LPP - 1, LPP);
  const float total = T0 + T1 + T2;                    // cs[192]
  const float E[3] = { i0 - q[0], T0 + i1 - q[1], T0 + T1 + i2 - q[2] };

  // ---- per-slot channel prefixes: p[s][k] = cs[64s + 4sub + k] ----
  float p[3][4];
#pragma unroll
  for (int s = 0; s < 3; ++s) {
    float run = E[s];
#pragma unroll
    for (int k = 0; k < 4; ++k) { p[s][k] = run; run = fmaf(xs[s][k], xs[s][k], run); }
  }

  // ---- head boundaries: hb0[s]=cs[64s+4sub-2], hb1[s]=cs[64s+4sub-1] ----
  float hb0[3], hb1[3];
#pragma unroll
  for (int s = 0; s < 3; ++s) {
    hb0[s] = __shfl_up(p[s][2], 1, LPP);
    hb1[s] = __shfl_up(p[s][3], 1, LPP);
  }
  const float B02 = __shfl(p[0][2], LPP - 1, LPP);   // cs[62]
  const float B03 = __shfl(p[0][3], LPP - 1, LPP);   // cs[63]
  const float B12 = __shfl(p[1][2], LPP - 1, LPP);   // cs[126]
  const float B13 = __shfl(p[1][3], LPP - 1, LPP);   // cs[127]
  if (sub == 0) {
    hb0[0] = 0.0f; hb1[0] = 0.0f;
    hb0[1] = B02;  hb1[1] = B03;
    hb0[2] = B12;  hb1[2] = B13;
  }

  // ---- gather cs[end], end = 2c+3 = 128s + 8sub + 2k + 3 (valid iff c <= 94) ----
  float ge0[4], ge1[4];
  {
    const float r00 = bperm(a0, p[0][3]), r01 = bperm(a0, p[1][3]);  // k=0
    const float r10 = bperm(a1, p[0][1]), r11 = bperm(a1, p[1][1]);  // k=1
    const float r20 = bperm(a1, p[0][3]), r21 = bperm(a1, p[1][3]);  // k=2
    const float r30 = bperm(a2, p[0][1]), r31 = bperm(a2, p[1][1]);  // k=3
    ge0[0] = (sub < 8) ? r00 : r01;
    ge0[1] = (sub < 8) ? r10 : r11;
    ge0[2] = (sub < 8) ? r20 : r21;
    ge0[3] = (sub < 7) ? r30 : r31;
    ge1[0] = bperm(a0, p[2][3]);
    ge1[1] = bperm(a1, p[2][1]);
    ge1[2] = bperm(a1, p[2][3]);
    ge1[3] = bperm(a2, p[2][1]);
  }

  // ---- windowed sums + series scale + coalesced NT stores ----
#pragma unroll
  for (int s = 0; s < 3; ++s) {
    float r[4];
#pragma unroll
    for (int k = 0; k < 4; ++k) {
      const float csh = (k >= 2) ? p[s][k - 2] : (k == 0 ? hb0[s] : hb1[s]);
      float cse;
      if (s == 0)      cse = ge0[k];
      else if (s == 1) cse = (4 * sub + k >= 31) ? total : ge1[k];
      else             cse = total;
      const float eps = (cse - csh) * AON;        // in [0, ~0.01]
      // (1+e)^-0.75 ~= 1 - 0.75e + 0.65625e^2 - 0.6015625e^3
      const float inv = fmaf(eps, fmaf(eps, fmaf(eps, -0.6015625f, 0.65625f), -0.75f), 1.0f);
      r[k] = xs[s][k] * inv;
    }
    nt_store4(r[0], r[1], r[2], r[3], &ob[16 * s + sub]);
  }
}

__global__ __launch_bounds__(BLOCK, 4) void lrn_kernel(
    const float* __restrict__ x, float* __restrict__ out, int npix) {
  const int tid  = threadIdx.x;
  const int lane = tid & 63;
  const int w    = tid >> 6;
  const int sub  = lane & 15;   // lane within pixel
  const int pl   = lane >> 4;   // pixel within wave

  const int slot   = blockIdx.x * WPB + w;   // wave-slot id
  const int nslots = gridDim.x * WPB;
  const int ngrp   = (npix + PPW - 1) / PPW; // pixel-groups (50176)
  int nit = (ngrp - slot + nslots - 1) / nslots;   // exactly 7 for this shape
  if (nit <= 0) return;

  // bpermute byte addresses (lane-only; hoisted out of the loop)
  const int gb = lane & 48;
  const int a0 = (gb | ((2 * sub)     & 15)) << 2;
  const int a1 = (gb | ((2 * sub + 1) & 15)) << 2;
  const int a2 = (gb | ((2 * sub + 2) & 15)) << 2;

  const float4* __restrict__ xb = (const float4*)x;
  const int nclamp = npix - 1;

  int grp = slot;
  int pix = grp * PPW + pl; if (pix > nclamp) pix = nclamp;
  int fb  = pix * (C / 4) + sub;             // float4 index of slot-0 quad
  float4 A0 = xb[fb], A1 = xb[fb + 16], A2 = xb[fb + 32];

  for (int t = 0; t < nit; ++t) {
    const int curfb = fb;                    // output base = input base (same layout)
    const int gn = grp + nslots;
    float4 B0, B1, B2;
    if (t + 1 < nit) {                       // slot-uniform branch
      int pixn = gn * PPW + pl; if (pixn > nclamp) pixn = nclamp;
      fb = pixn * (C / 4) + sub;
      B0 = xb[fb]; B1 = xb[fb + 16]; B2 = xb[fb + 32];   // issue next loads FIRST
    }
    float4* ob = (float4*)out + (curfb - sub);           // pixel row base
    lrn_body(A0, A1, A2, ob, sub, a0, a1, a2);
    grp = gn;
    A0 = B0; A1 = B1; A2 = B2;
  }
}

extern "C" void kernel_launch(void* const* d_in, const int* in_sizes, int n_in,
                              void* d_out, int out_size, void* d_ws, size_t ws_size,
                              hipStream_t stream) {
  const float* x   = (const float*)d_in[0];
  float*       out = (float*)d_out;
  const int npix = in_sizes[0] / C;                  // 64*56*56 = 200704
  const int ngrp = (npix + PPW - 1) / PPW;           // 50176
  int grid = (ngrp + WPB - 1) / WPB;                 // cap for tiny inputs
  if (grid > GRID) grid = GRID;                      // 1792 -> 7168 slots, 7 iters each
  lrn_kernel<<<grid, BLOCK, 0, stream>>>(x, out, npix);
}